// Round 6
// baseline (510.734 us; speedup 1.0000x reference)
//
#include <hip/hip_runtime.h>

typedef unsigned short u16;
typedef unsigned int   u32;
typedef float f32x4 __attribute__((ext_vector_type(4)));
typedef int   i32x4 __attribute__((ext_vector_type(4)));
typedef int   i32x2 __attribute__((ext_vector_type(2)));
typedef short s8v   __attribute__((ext_vector_type(8)));

// ---------- helpers ----------
__device__ inline u16 f2bf(float f) {
  u32 u = __float_as_uint(f);
  return (u16)((u + 0x7FFFu + ((u >> 16) & 1u)) >> 16);
}
__device__ inline float bf2f(u16 h) { return __uint_as_float(((u32)h) << 16); }

__device__ inline u32 fkey(float f) {
  u32 u = __float_as_uint(f);
  return (u & 0x80000000u) ? ~u : (u | 0x80000000u);
}
__device__ inline float unkey(u32 k) {
  u32 u = (k & 0x80000000u) ? (k & 0x7FFFFFFFu) : ~k;
  return __uint_as_float(u);
}
__device__ inline float fast_tanh(float x) {
  float cx = fminf(fmaxf(x, -15.f), 15.f);
  float e = __expf(2.f * cx);
  return __fdividef(e - 1.f, e + 1.f);
}
__device__ inline float sigm(float x) { return __fdividef(1.f, 1.f + __expf(-x)); }

struct MlpP { const float *W1,*b1,*g1,*bb1,*W2,*b2,*g2,*bb2,*W3,*b3; };

// 5 -> 16(LN,tanh) -> 8(LN,tanh) -> 3(sigmoid)
__device__ inline void mlp_eval(const MlpP& p, const float* s, float* ctl) {
  float h1[16];
  float mu = 0.f;
  #pragma unroll
  for (int i = 0; i < 16; ++i) {
    float v = p.b1[i];
    #pragma unroll
    for (int k = 0; k < 5; ++k) v = fmaf(p.W1[i*5+k], s[k], v);
    h1[i] = v; mu += v;
  }
  mu *= (1.0f/16.0f);
  float vv = 0.f;
  #pragma unroll
  for (int i = 0; i < 16; ++i) { float d = h1[i]-mu; vv += d*d; }
  vv *= (1.0f/16.0f);
  float inv = 1.0f/sqrtf(vv + 1e-5f);
  #pragma unroll
  for (int i = 0; i < 16; ++i) h1[i] = fast_tanh((h1[i]-mu)*inv*p.g1[i] + p.bb1[i]);
  float h2[8];
  mu = 0.f;
  #pragma unroll
  for (int o = 0; o < 8; ++o) {
    float v = p.b2[o];
    #pragma unroll
    for (int i = 0; i < 16; ++i) v = fmaf(p.W2[o*16+i], h1[i], v);
    h2[o] = v; mu += v;
  }
  mu *= 0.125f;
  vv = 0.f;
  #pragma unroll
  for (int o = 0; o < 8; ++o) { float d = h2[o]-mu; vv += d*d; }
  vv *= 0.125f;
  inv = 1.0f/sqrtf(vv + 1e-5f);
  #pragma unroll
  for (int o = 0; o < 8; ++o) h2[o] = fast_tanh((h2[o]-mu)*inv*p.g2[o] + p.bb2[o]);
  #pragma unroll
  for (int c = 0; c < 3; ++c) {
    float v = p.b3[c];
    #pragma unroll
    for (int o = 0; o < 8; ++o) v = fmaf(p.W3[c*8+o], h2[o], v);
    ctl[c] = sigm(v);
  }
}

// ---------- K0: merged pre-kernel: cast X, cast W_embed, cast Ws/Wf, init S ----------
__global__ __launch_bounds__(256) void k_pre(const float* __restrict__ x,
                                             const float* __restrict__ We,
                                             const float* __restrict__ Ws,
                                             const float* __restrict__ Wf,
                                             u16* __restrict__ Xb, u16* __restrict__ Wb,
                                             u16* __restrict__ WsB, u16* __restrict__ WfB,
                                             float* __restrict__ S) {
  const int bi = blockIdx.x, t = threadIdx.x;
  if (bi < 2048) {
    const float* src = (bi < 1024) ? x : We;
    u16* dst = (bi < 1024) ? Xb : Wb;
    int i = ((bi & 1023) * 256 + t) * 4;
    f32x4 v = *(const f32x4*)(src + i);
    u16 o[4] = { f2bf(v[0]), f2bf(v[1]), f2bf(v[2]), f2bf(v[3]) };
    *(u32*)(dst + i)     = ((u32)o[1] << 16) | o[0];
    *(u32*)(dst + i + 2) = ((u32)o[3] << 16) | o[2];
  } else {
    // cast W_slow / W_fast (4096 elems each): 16 elems per thread
    #pragma unroll
    for (int m = 0; m < 2; ++m) {
      const float* src = m ? Wf : Ws;
      u16* dst = m ? WfB : WsB;
      int base = t * 16;
      u16 o[16];
      #pragma unroll
      for (int r = 0; r < 4; ++r) {
        f32x4 v = *(const f32x4*)(src + base + r*4);
        o[r*4+0]=f2bf(v[0]); o[r*4+1]=f2bf(v[1]); o[r*4+2]=f2bf(v[2]); o[r*4+3]=f2bf(v[3]);
      }
      #pragma unroll
      for (int r = 0; r < 8; ++r)
        *(u32*)(dst + base + r*2) = ((u32)o[r*2+1] << 16) | o[r*2];
    }
    if (t < 3) S[t] = 0.f;
    if (t == 3) ((u32*)S)[3] = 0xFFFFFFFFu;  // min key
    if (t == 4) ((u32*)S)[4] = 0u;           // max key
  }
}

// ---------- K1: e = x @ W_embed.T + b_embed, fused global stats ----------
// 64x64 tile, single-stage K=256 (reg-staged into PADDED LDS, one barrier,
// then pure MFMA). X/W panels are 2MB bf16 each -> L2/L3-hot. XCD swizzle.
__global__ __launch_bounds__(256) void k_gemm(const u16* __restrict__ Xb,
                                              const u16* __restrict__ Wb,
                                              const float* __restrict__ bias,
                                              u16* __restrict__ E,
                                              float* __restrict__ S) {
  __shared__ __align__(16) u16 As[64*264];   // row stride 264 u16 = 528B (33*16B): 2-way max
  __shared__ __align__(16) u16 Bs[64*264];
  const int t = threadIdx.x;
  const int wv = t >> 6, lane = t & 63;
  const int wr = wv >> 1, wc = wv & 1;
  const int bid = blockIdx.x;
  const int sw = (bid & 7) * 512 + (bid >> 3);      // bijective: 4096 % 8 == 0
  const int i0 = (sw >> 6) * 64, j0 = (sw & 63) * 64;
  const int rr = lane & 15, q = lane >> 4;

  // ---- stage A and B (8 x 16B chunks per thread per matrix), padded LDS ----
  #pragma unroll
  for (int k = 0; k < 8; ++k) {
    const int e = (k*256 + t) * 8;                  // elem in 64x256
    const int row = e >> 8, col = e & 255;
    i32x4 va = *(const i32x4*)(Xb + (size_t)(i0 + row)*256 + col);
    i32x4 vb = *(const i32x4*)(Wb + (size_t)(j0 + row)*256 + col);
    *(i32x4*)&As[row*264 + col] = va;
    *(i32x4*)&Bs[row*264 + col] = vb;
  }
  __syncthreads();

  // ---- 32 MFMA straight (wave -> 32x32 output, 2x2 frags x 8 k-slices) ----
  f32x4 acc[2][2] = {};
  #pragma unroll
  for (int ks = 0; ks < 8; ++ks) {
    s8v a[2], b[2];
    a[0] = *(const s8v*)&As[(wr*32 +      rr)*264 + ks*32 + q*8];
    a[1] = *(const s8v*)&As[(wr*32 + 16 + rr)*264 + ks*32 + q*8];
    b[0] = *(const s8v*)&Bs[(wc*32 +      rr)*264 + ks*32 + q*8];
    b[1] = *(const s8v*)&Bs[(wc*32 + 16 + rr)*264 + ks*32 + q*8];
    #pragma unroll
    for (int m = 0; m < 2; ++m)
      #pragma unroll
      for (int n = 0; n < 2; ++n)
        acc[m][n] = __builtin_amdgcn_mfma_f32_16x16x32_bf16(a[m], b[n], acc[m][n], 0, 0, 0);
  }

  // ---- epilogue: bias + store bf16 + fused global stats ----
  float s = 0.f, ss = 0.f, sa = 0.f, mnv = 1e30f, mxv = -1e30f;
  #pragma unroll
  for (int n = 0; n < 2; ++n) {
    const int col = j0 + wc*32 + n*16 + rr;
    const float bv = bias[col];
    #pragma unroll
    for (int m = 0; m < 2; ++m) {
      const int rowb = i0 + wr*32 + m*16 + q*4;
      #pragma unroll
      for (int r = 0; r < 4; ++r) {
        float v = acc[m][n][r] + bv;
        E[(size_t)(rowb + r)*4096 + col] = f2bf(v);
        s += v; ss = fmaf(v, v, ss); sa += fabsf(v);
        mnv = fminf(mnv, v); mxv = fmaxf(mxv, v);
      }
    }
  }
  #pragma unroll
  for (int off = 32; off; off >>= 1) {
    s += __shfl_xor(s, off); ss += __shfl_xor(ss, off); sa += __shfl_xor(sa, off);
    mnv = fminf(mnv, __shfl_xor(mnv, off));
    mxv = fmaxf(mxv, __shfl_xor(mxv, off));
  }
  __shared__ float red5[4][5];
  if (lane == 0) { red5[wv][0]=s; red5[wv][1]=ss; red5[wv][2]=sa; red5[wv][3]=mnv; red5[wv][4]=mxv; }
  __syncthreads();
  if (t == 0) {
    float S0 = red5[0][0]+red5[1][0]+red5[2][0]+red5[3][0];
    float S1 = red5[0][1]+red5[1][1]+red5[2][1]+red5[3][1];
    float S2 = red5[0][2]+red5[1][2]+red5[2][2]+red5[3][2];
    float Mn = fminf(fminf(red5[0][3],red5[1][3]), fminf(red5[2][3],red5[3][3]));
    float Mx = fmaxf(fmaxf(red5[0][4],red5[1][4]), fmaxf(red5[2][4],red5[3][4]));
    atomicAdd(&S[0], S0); atomicAdd(&S[1], S1); atomicAdd(&S[2], S2);
    atomicMin((u32*)S + 3, fkey(Mn));
    atomicMax((u32*)S + 4, fkey(Mx));
  }
}

// ---------- K2: t-regulator -> ap -> normalized sparse adjacency ----------
__global__ __launch_bounds__(256) void k_prep(const float* __restrict__ adjw,
    const float* __restrict__ Wslow,
    const float* tW1, const float* tb1, const float* tg1, const float* tbb1,
    const float* tW2, const float* tb2, const float* tg2, const float* tbb2,
    const float* tW3, const float* tb3,
    float* __restrict__ S) {
  __shared__ float red[2][256];
  __shared__ float apL;
  const int t = threadIdx.x;
  float a = 0.f, w = 0.f;
  for (int i = t; i < 4096; i += 256) {
    float v = adjw[i]; a = fmaf(v, v, a);
    float u = Wslow[i]; w = fmaf(u, u, w);
  }
  red[0][t] = a; red[1][t] = w;
  __syncthreads();
  for (int sred = 128; sred > 0; sred >>= 1) {
    if (t < sred) { red[0][t] += red[0][t+sred]; red[1][t] += red[1][t+sred]; }
    __syncthreads();
  }
  if (t == 0) {
    float wn_t = sqrtf(red[0][0]);
    float wn_c = sqrtf(red[1][0]);
    S[7] = wn_c;
    const float n = 16777216.0f, n1 = 16777215.0f;
    float sum = S[0], sumsq = S[1], sumabs = S[2];
    float mean = sum / n;
    float var = (sumsq - sum*mean) / n1;             // ddof=1
    float mn = unkey(((u32*)S)[3]);
    float mx = unkey(((u32*)S)[4]);
    float sfv[5];
    sfv[0] = fabsf(var - 0.5f);
    sfv[1] = fabsf((mx - mn)/n1 - 1.0f);             // sort-free smoothness
    sfv[2] = sumabs / n;
    sfv[3] = wn_t;
    sfv[4] = sqrtf(sumsq / n);
    MlpP p{tW1,tb1,tg1,tbb1,tW2,tb2,tg2,tbb2,tW3,tb3};
    float ctl[3];
    mlp_eval(p, sfv, ctl);
    apL = ctl[0];
    S[6] = ctl[0];
  }
  __syncthreads();
  if (t < 64) {
    const int rr = t >> 3, cc = t & 7;
    const float ap = apL;
    const int nb[4] = { rr>0 ? t-8 : -1, rr<7 ? t+8 : -1, cc>0 ? t-1 : -1, cc<7 ? t+1 : -1 };
    float w4[4]; float rs = 0.f;
    #pragma unroll
    for (int qq = 0; qq < 4; ++qq) {
      w4[qq] = (nb[qq] >= 0) ? sigm(adjw[t*64 + nb[qq]] * ap) : 0.0f;
      rs += w4[qq];
    }
    rs = fmaxf(rs, 1e-6f);
    #pragma unroll
    for (int qq = 0; qq < 4; ++qq) S[8 + t*4 + qq] = w4[qq] / rs;
  }
}

// ---------- K3: fused message-pass + cell + readout, v5 ----------
// NO min-waves launch bound: (256,5) and (256,4) both forced register spill
// (r3: 377MB, r4: 213MB scratch writes). Natural allocation (r2: VGPR 108,
// zero spill) is the proven-clean point. Per-node scratch in each row's own
// 16B pad ebM[n][64..71] (only the owning wave touches it: race-free).
__global__ __launch_bounds__(256) void k_cell(const u16* __restrict__ E,
    const u16* __restrict__ WsB, const u16* __restrict__ WfB,
    const float* __restrict__ lng, const float* __restrict__ lnb,
    const float* __restrict__ Wread, const float* __restrict__ bread,
    const float* __restrict__ S,
    const float* cW1, const float* cb1, const float* cg1, const float* cbb1,
    const float* cW2, const float* cb2, const float* cg2, const float* cbb2,
    const float* cW3, const float* cb3,
    float* __restrict__ out) {
  __shared__ __align__(16) u16 ebM[64][72];   // e -> m (overlay); cols 64..71 = per-row f32x4 scratch
  __shared__ __align__(16) u16 WsH[64][72];   // W_slow bf16 [j][d]
  __shared__ __align__(16) u16 WfH[64][72];
  __shared__ __align__(16) float adjcL[256];
  __shared__ __align__(16) float prm[308];
  __shared__ __align__(16) float lngL[64], lnbL[64];
  __shared__ float wavp[4][10];
  __shared__ float wncL;

  const int t = threadIdx.x;
  const int wv = t >> 6, lane = t & 63;
  const int b = blockIdx.x;
  const u16* Eb = E + (size_t)b * 4096;

  // ---- P1: loads (16 u16 per thread per matrix, quarter-row chunks) ----
  {
    const int row = t >> 2, c16 = (t & 3) * 16;
    *(i32x4*)&ebM[row][c16]     = *(const i32x4*)(Eb  + row*64 + c16);
    *(i32x4*)&ebM[row][c16 + 8] = *(const i32x4*)(Eb  + row*64 + c16 + 8);
    *(i32x4*)&WsH[row][c16]     = *(const i32x4*)(WsB + row*64 + c16);
    *(i32x4*)&WsH[row][c16 + 8] = *(const i32x4*)(WsB + row*64 + c16 + 8);
    *(i32x4*)&WfH[row][c16]     = *(const i32x4*)(WfB + row*64 + c16);
    *(i32x4*)&WfH[row][c16 + 8] = *(const i32x4*)(WfB + row*64 + c16 + 8);
  }
  adjcL[t] = S[8 + t];
  for (int i = t; i < 80;  i += 256) prm[i] = cW1[i];
  if (t < 16) { prm[80+t]=cb1[t]; prm[96+t]=cg1[t]; prm[112+t]=cbb1[t]; }
  for (int i = t; i < 128; i += 256) prm[128+i] = cW2[i];
  if (t < 8)  { prm[256+t]=cb2[t]; prm[264+t]=cg2[t]; prm[272+t]=cbb2[t]; }
  if (t < 24) prm[280+t] = cW3[t];
  if (t < 3)  prm[304+t] = cb3[t];
  if (t < 64) { lngL[t] = lng[t]; lnbL[t] = lnb[t]; }
  if (t == 0) wncL = S[7];
  __syncthreads();

  // ---- P2: message passing into registers; wave wv owns nodes wv*16..+15 ----
  float macc[16];
  {
    const int d = lane;
    #pragma unroll
    for (int i = 0; i < 16; ++i) {
      const int n = wv*16 + i;
      const int gr = n >> 3, gc = n & 7;
      const int nb0 = gr > 0 ? n - 8 : 0;
      const int nb1 = gr < 7 ? n + 8 : 0;
      const int nb2 = gc > 0 ? n - 1 : 0;
      const int nb3 = gc < 7 ? n + 1 : 0;
      macc[i] = adjcL[n*4+0]*bf2f(ebM[nb0][d]) + adjcL[n*4+1]*bf2f(ebM[nb1][d])
              + adjcL[n*4+2]*bf2f(ebM[nb2][d]) + adjcL[n*4+3]*bf2f(ebM[nb3][d]);
    }
  }
  __syncthreads();   // all e reads done
  #pragma unroll
  for (int i = 0; i < 16; ++i) ebM[wv*16 + i][lane] = f2bf(macc[i]);  // m overlays e
  __syncthreads();

  // ---- P3: MFMA hsT/hfT; frags feed stats ----
  const int rr = lane & 15, q = lane >> 4;
  const int n = wv*16 + rr;
  s8v bm0 = *(const s8v*)&ebM[n][q*8];
  s8v bm1 = *(const s8v*)&ebM[n][32 + q*8];
  f32x4 hs[4], hf[4];
  #pragma unroll
  for (int jt = 0; jt < 4; ++jt) {
    const u16* wsr = &WsH[jt*16 + rr][0];
    const u16* wfr = &WfH[jt*16 + rr][0];
    s8v aw0 = *(const s8v*)(wsr + q*8), aw1 = *(const s8v*)(wsr + 32 + q*8);
    s8v af0 = *(const s8v*)(wfr + q*8), af1 = *(const s8v*)(wfr + 32 + q*8);
    f32x4 z = {0.f, 0.f, 0.f, 0.f};
    hs[jt] = __builtin_amdgcn_mfma_f32_16x16x32_bf16(aw0, bm0, z, 0, 0, 0);
    hs[jt] = __builtin_amdgcn_mfma_f32_16x16x32_bf16(aw1, bm1, hs[jt], 0, 0, 0);
    hf[jt] = __builtin_amdgcn_mfma_f32_16x16x32_bf16(af0, bm0, z, 0, 0, 0);
    hf[jt] = __builtin_amdgcn_mfma_f32_16x16x32_bf16(af1, bm1, hf[jt], 0, 0, 0);
  }

  // ---- P4: per-node stats (reduce over q); q==0 lane stores into own row pad ----
  float s1 = 0.f, s2 = 0.f, mnv = 1e30f, mxv = -1e30f;
  #pragma unroll
  for (int j = 0; j < 8; ++j) {
    float v0 = bf2f((u16)bm0[j]), v1 = bf2f((u16)bm1[j]);
    s1 += v0 + v1;
    s2 = fmaf(v0, v0, s2); s2 = fmaf(v1, v1, s2);
    mnv = fminf(mnv, fminf(v0, v1));
    mxv = fmaxf(mxv, fmaxf(v0, v1));
  }
  float sa = 0.f, sq = 0.f;
  #pragma unroll
  for (int jt = 0; jt < 4; ++jt)
    #pragma unroll
    for (int r = 0; r < 4; ++r) { float v = hs[jt][r]; sa += fabsf(v); sq = fmaf(v, v, sq); }
  #pragma unroll
  for (int off = 16; off <= 32; off <<= 1) {
    s1 += __shfl_xor(s1, off); s2 += __shfl_xor(s2, off);
    sa += __shfl_xor(sa, off); sq += __shfl_xor(sq, off);
    mnv = fminf(mnv, __shfl_xor(mnv, off));
    mxv = fmaxf(mxv, __shfl_xor(mxv, off));
  }
  if (q == 0) {
    float var = (s2 - s1*s1*(1.f/64.f)) * (1.f/63.f);   // ddof=1
    f32x4 sv = { fabsf(var - 0.5f),
                 fabsf((mxv - mnv)*(1.f/63.f) - 1.f),
                 sa * (1.f/64.f),
                 sqrtf(sq * (1.f/64.f)) };
    *(f32x4*)&ebM[n][64] = sv;                          // own wave's row: race-free
  }
  __syncthreads();

  // ---- P4b: ONE wave computes all 64 node-MLPs (lane = node) ----
  if (t < 64) {
    f32x4 sv = *(const f32x4*)&ebM[t][64];
    float sfv[5] = { sv[0], sv[1], sv[2], wncL, sv[3] };
    MlpP p{prm, prm+80, prm+96, prm+112, prm+128, prm+256, prm+264, prm+272, prm+280, prm+304};
    float ctl[3];
    mlp_eval(p, sfv, ctl);
    float* pad = (float*)&ebM[t][64];
    pad[0] = 0.5f + 2.f*ctl[1];                         // beta
    pad[1] = ctl[2];                                    // gate
  }
  __syncthreads();

  // ---- P5: comb -> swish -> LN -> fused readout ----
  const float beta = ((const float*)&ebM[n][64])[0];
  const float gate = ((const float*)&ebM[n][64])[1];
  float acts[4][4];
  float a1 = 0.f, a2 = 0.f;
  #pragma unroll
  for (int jt = 0; jt < 4; ++jt)
    #pragma unroll
    for (int r = 0; r < 4; ++r) {
      float comb = fmaf(hf[jt][r], gate, hs[jt][r]);
      float sv = comb * sigm(beta * comb);
      acts[jt][r] = sv;
      a1 += sv; a2 = fmaf(sv, sv, a2);
    }
  a1 += __shfl_xor(a1, 16); a2 += __shfl_xor(a2, 16);
  a1 += __shfl_xor(a1, 32); a2 += __shfl_xor(a2, 32);
  float mu = a1 * (1.f/64.f);
  float vvv = a2 * (1.f/64.f) - mu*mu;                 // ddof=0
  float inv = 1.f / sqrtf(vvv + 1e-5f);
  float racc[10];
  #pragma unroll
  for (int c = 0; c < 10; ++c) racc[c] = 0.f;
  #pragma unroll
  for (int jt = 0; jt < 4; ++jt) {
    f32x4 gv = *(const f32x4*)&lngL[jt*16 + q*4];
    f32x4 bv = *(const f32x4*)&lnbL[jt*16 + q*4];
    float pr[4];
    #pragma unroll
    for (int r = 0; r < 4; ++r) pr[r] = (acts[jt][r] - mu)*inv*gv[r] + bv[r];
    const float* wrb = Wread + n*64 + jt*16 + q*4;
    #pragma unroll
    for (int c = 0; c < 10; ++c) {
      f32x4 w = *(const f32x4*)(wrb + c*4096);
      racc[c] += pr[0]*w[0] + pr[1]*w[1] + pr[2]*w[2] + pr[3]*w[3];
    }
  }
  #pragma unroll
  for (int c = 0; c < 10; ++c) {
    float v = racc[c];
    #pragma unroll
    for (int off = 1; off < 64; off <<= 1) v += __shfl_xor(v, off);
    if (lane == 0) wavp[wv][c] = v;
  }
  __syncthreads();
  if (t < 10) out[(size_t)b*10 + t] = bread[t] + wavp[0][t] + wavp[1][t] + wavp[2][t] + wavp[3][t];
}

// ---------- launcher ----------
extern "C" void kernel_launch(void* const* d_in, const int* in_sizes, int n_in,
                              void* d_out, int out_size, void* d_ws, size_t ws_size,
                              hipStream_t stream) {
  (void)in_sizes; (void)n_in; (void)out_size; (void)ws_size;
  const float* x       = (const float*)d_in[0];
  const float* W_embed = (const float*)d_in[1];
  const float* b_embed = (const float*)d_in[2];
  const float* adjw    = (const float*)d_in[3];
  const float* Wslow   = (const float*)d_in[4];
  const float* Wfast   = (const float*)d_in[5];
  const float* lng     = (const float*)d_in[6];
  const float* lnb     = (const float*)d_in[7];
  const float* Wread   = (const float*)d_in[8];
  const float* bread   = (const float*)d_in[9];
  float* out = (float*)d_out;

  char* ws = (char*)d_ws;
  u16*   Ebf  = (u16*)ws;                              // 33554432 B
  u16*   Xbf  = (u16*)(ws + 33554432);                 // 2097152 B
  u16*   Wbf  = (u16*)(ws + 35651584);                 // 2097152 B
  float* S    = (float*)(ws + 37748736);               // 4096 B (stats + adjc)
  u16*   WsBf = (u16*)(ws + 37752832);                 // 8192 B
  u16*   WfBf = (u16*)(ws + 37761024);                 // 8192 B

  hipLaunchKernelGGL(k_pre, dim3(2049), dim3(256), 0, stream,
                     x, W_embed, Wslow, Wfast, Xbf, Wbf, WsBf, WfBf, S);
  hipLaunchKernelGGL(k_gemm, dim3(4096), dim3(256), 0, stream, Xbf, Wbf, b_embed, Ebf, S);
  hipLaunchKernelGGL(k_prep, dim3(1), dim3(256), 0, stream, adjw, Wslow,
                     (const float*)d_in[10], (const float*)d_in[11], (const float*)d_in[12], (const float*)d_in[13],
                     (const float*)d_in[14], (const float*)d_in[15], (const float*)d_in[16], (const float*)d_in[17],
                     (const float*)d_in[18], (const float*)d_in[19], S);
  hipLaunchKernelGGL(k_cell, dim3(4096), dim3(256), 0, stream, Ebf, WsBf, WfBf, lng, lnb,
                     Wread, bread, S,
                     (const float*)d_in[20], (const float*)d_in[21], (const float*)d_in[22], (const float*)d_in[23],
                     (const float*)d_in[24], (const float*)d_in[25], (const float*)d_in[26], (const float*)d_in[27],
                     (const float*)d_in[28], (const float*)d_in[29], out);
}

// Round 7
// 349.449 us; speedup vs baseline: 1.4615x; 1.4615x over previous
//
#include <hip/hip_runtime.h>

typedef unsigned short u16;
typedef unsigned int   u32;
typedef float f32x4 __attribute__((ext_vector_type(4)));
typedef int   i32x4 __attribute__((ext_vector_type(4)));
typedef int   i32x2 __attribute__((ext_vector_type(2)));
typedef short s8v   __attribute__((ext_vector_type(8)));

// ---------- helpers ----------
__device__ inline u16 f2bf(float f) {
  u32 u = __float_as_uint(f);
  return (u16)((u + 0x7FFFu + ((u >> 16) & 1u)) >> 16);
}
__device__ inline float bf2f(u16 h) { return __uint_as_float(((u32)h) << 16); }

__device__ inline u32 fkey(float f) {
  u32 u = __float_as_uint(f);
  return (u & 0x80000000u) ? ~u : (u | 0x80000000u);
}
__device__ inline float unkey(u32 k) {
  u32 u = (k & 0x80000000u) ? (k & 0x7FFFFFFFu) : ~k;
  return __uint_as_float(u);
}
__device__ inline float fast_tanh(float x) {
  float cx = fminf(fmaxf(x, -15.f), 15.f);
  float e = __expf(2.f * cx);
  return __fdividef(e - 1.f, e + 1.f);
}
__device__ inline float sigm(float x) { return __fdividef(1.f, 1.f + __expf(-x)); }

__device__ inline void gload_lds16(const u16* g, u16* l) {
  __builtin_amdgcn_global_load_lds((const __attribute__((address_space(1))) u32*)g,
                                   (__attribute__((address_space(3))) u32*)l, 16, 0, 0);
}

struct MlpP { const float *W1,*b1,*g1,*bb1,*W2,*b2,*g2,*bb2,*W3,*b3; };

// 5 -> 16(LN,tanh) -> 8(LN,tanh) -> 3(sigmoid)
__device__ inline void mlp_eval(const MlpP& p, const float* s, float* ctl) {
  float h1[16];
  float mu = 0.f;
  #pragma unroll
  for (int i = 0; i < 16; ++i) {
    float v = p.b1[i];
    #pragma unroll
    for (int k = 0; k < 5; ++k) v = fmaf(p.W1[i*5+k], s[k], v);
    h1[i] = v; mu += v;
  }
  mu *= (1.0f/16.0f);
  float vv = 0.f;
  #pragma unroll
  for (int i = 0; i < 16; ++i) { float d = h1[i]-mu; vv += d*d; }
  vv *= (1.0f/16.0f);
  float inv = 1.0f/sqrtf(vv + 1e-5f);
  #pragma unroll
  for (int i = 0; i < 16; ++i) h1[i] = fast_tanh((h1[i]-mu)*inv*p.g1[i] + p.bb1[i]);
  float h2[8];
  mu = 0.f;
  #pragma unroll
  for (int o = 0; o < 8; ++o) {
    float v = p.b2[o];
    #pragma unroll
    for (int i = 0; i < 16; ++i) v = fmaf(p.W2[o*16+i], h1[i], v);
    h2[o] = v; mu += v;
  }
  mu *= 0.125f;
  vv = 0.f;
  #pragma unroll
  for (int o = 0; o < 8; ++o) { float d = h2[o]-mu; vv += d*d; }
  vv *= 0.125f;
  inv = 1.0f/sqrtf(vv + 1e-5f);
  #pragma unroll
  for (int o = 0; o < 8; ++o) h2[o] = fast_tanh((h2[o]-mu)*inv*p.g2[o] + p.bb2[o]);
  #pragma unroll
  for (int c = 0; c < 3; ++c) {
    float v = p.b3[c];
    #pragma unroll
    for (int o = 0; o < 8; ++o) v = fmaf(p.W3[c*8+o], h2[o], v);
    ctl[c] = sigm(v);
  }
}

// ---------- K0: merged pre-kernel: cast X/W_embed/Ws/Wf, norms, init S ----------
__global__ __launch_bounds__(256) void k_pre(const float* __restrict__ x,
                                             const float* __restrict__ We,
                                             const float* __restrict__ Ws,
                                             const float* __restrict__ Wf,
                                             const float* __restrict__ adjw,
                                             u16* __restrict__ Xb, u16* __restrict__ Wb,
                                             u16* __restrict__ WsB, u16* __restrict__ WfB,
                                             float* __restrict__ S) {
  const int bi = blockIdx.x, t = threadIdx.x;
  if (bi < 2048) {
    const float* src = (bi < 1024) ? x : We;
    u16* dst = (bi < 1024) ? Xb : Wb;
    int i = ((bi & 1023) * 256 + t) * 4;
    f32x4 v = *(const f32x4*)(src + i);
    u16 o[4] = { f2bf(v[0]), f2bf(v[1]), f2bf(v[2]), f2bf(v[3]) };
    *(u32*)(dst + i)     = ((u32)o[1] << 16) | o[0];
    *(u32*)(dst + i + 2) = ((u32)o[3] << 16) | o[2];
  } else {
    // cast W_slow / W_fast (4096 elems each): 16 elems per thread
    #pragma unroll
    for (int m = 0; m < 2; ++m) {
      const float* src = m ? Wf : Ws;
      u16* dst = m ? WfB : WsB;
      int base = t * 16;
      u16 o[16];
      #pragma unroll
      for (int r = 0; r < 4; ++r) {
        f32x4 v = *(const f32x4*)(src + base + r*4);
        o[r*4+0]=f2bf(v[0]); o[r*4+1]=f2bf(v[1]); o[r*4+2]=f2bf(v[2]); o[r*4+3]=f2bf(v[3]);
      }
      #pragma unroll
      for (int r = 0; r < 8; ++r)
        *(u32*)(dst + base + r*2) = ((u32)o[r*2+1] << 16) | o[r*2];
    }
    // Frobenius norms of adj_weights (wn_t) and W_slow (wn_c)
    __shared__ float red2[2][256];
    float a = 0.f, w = 0.f;
    for (int i = t; i < 4096; i += 256) {
      float v = adjw[i]; a = fmaf(v, v, a);
      float u = Ws[i];   w = fmaf(u, u, w);
    }
    red2[0][t] = a; red2[1][t] = w;
    __syncthreads();
    for (int sred = 128; sred > 0; sred >>= 1) {
      if (t < sred) { red2[0][t] += red2[0][t+sred]; red2[1][t] += red2[1][t+sred]; }
      __syncthreads();
    }
    if (t == 0) { S[5] = sqrtf(red2[0][0]); S[7] = sqrtf(red2[1][0]); }
    if (t < 3) S[t] = 0.f;
    if (t == 3) ((u32*)S)[3] = 0xFFFFFFFFu;  // min key
    if (t == 4) ((u32*)S)[4] = 0u;           // max key
  }
}

// ---------- K1: e = x @ W_embed.T + b_embed, fused global stats ----------
// r2-proven structure: 128x128 tile, BK=64, single-buffer 32KB LDS (4-5
// blocks/CU), global_load_lds w=16. + bijective XCD swizzle (1024%8==0).
__global__ __launch_bounds__(256) void k_gemm(const u16* __restrict__ Xb,
                                              const u16* __restrict__ Wb,
                                              const float* __restrict__ bias,
                                              u16* __restrict__ E,
                                              float* __restrict__ S) {
  __shared__ __align__(16) u16 As[128*64];
  __shared__ __align__(16) u16 Bs[128*64];
  const int t = threadIdx.x;
  const int wv = t >> 6, lane = t & 63;
  const int wr = wv >> 1, wc = wv & 1;
  const int bid = blockIdx.x;
  const int sw = (bid & 7) * 128 + (bid >> 3);     // bijective: 1024 % 8 == 0
  const int i0 = (sw >> 5) * 128, j0 = (sw & 31) * 128;
  const int rr = lane & 15, q = lane >> 4;
  const int lrow = lane >> 3, lcol = (lane & 7) * 8;
  f32x4 acc[4][4] = {};
  for (int k0 = 0; k0 < 256; k0 += 64) {
    #pragma unroll
    for (int r = 0; r < 4; ++r) {
      const int row = (r*4 + wv)*8 + lrow;
      gload_lds16(Xb + (size_t)(i0 + row)*256 + k0 + lcol, &As[(r*4 + wv)*512]);
      gload_lds16(Wb + (size_t)(j0 + row)*256 + k0 + lcol, &Bs[(r*4 + wv)*512]);
    }
    __syncthreads();
    #pragma unroll
    for (int ks = 0; ks < 2; ++ks) {
      s8v a[4], b[4];
      #pragma unroll
      for (int m = 0; m < 4; ++m) a[m] = *(const s8v*)&As[(wr*64 + m*16 + rr)*64 + ks*32 + q*8];
      #pragma unroll
      for (int n = 0; n < 4; ++n) b[n] = *(const s8v*)&Bs[(wc*64 + n*16 + rr)*64 + ks*32 + q*8];
      #pragma unroll
      for (int m = 0; m < 4; ++m)
        #pragma unroll
        for (int n = 0; n < 4; ++n)
          acc[m][n] = __builtin_amdgcn_mfma_f32_16x16x32_bf16(a[m], b[n], acc[m][n], 0, 0, 0);
    }
    __syncthreads();
  }
  float s = 0.f, ss = 0.f, sa = 0.f, mnv = 1e30f, mxv = -1e30f;
  #pragma unroll
  for (int n = 0; n < 4; ++n) {
    const int col = j0 + wc*64 + n*16 + rr;
    const float bv = bias[col];
    #pragma unroll
    for (int m = 0; m < 4; ++m) {
      const int rowb = i0 + wr*64 + m*16 + q*4;
      #pragma unroll
      for (int r = 0; r < 4; ++r) {
        float v = acc[m][n][r] + bv;
        E[(size_t)(rowb + r)*4096 + col] = f2bf(v);
        s += v; ss = fmaf(v, v, ss); sa += fabsf(v);
        mnv = fminf(mnv, v); mxv = fmaxf(mxv, v);
      }
    }
  }
  #pragma unroll
  for (int off = 32; off; off >>= 1) {
    s += __shfl_xor(s, off); ss += __shfl_xor(ss, off); sa += __shfl_xor(sa, off);
    mnv = fminf(mnv, __shfl_xor(mnv, off));
    mxv = fmaxf(mxv, __shfl_xor(mxv, off));
  }
  __shared__ float red5[4][5];
  if (lane == 0) { red5[wv][0]=s; red5[wv][1]=ss; red5[wv][2]=sa; red5[wv][3]=mnv; red5[wv][4]=mxv; }
  __syncthreads();
  if (t == 0) {
    float S0 = red5[0][0]+red5[1][0]+red5[2][0]+red5[3][0];
    float S1 = red5[0][1]+red5[1][1]+red5[2][1]+red5[3][1];
    float S2 = red5[0][2]+red5[1][2]+red5[2][2]+red5[3][2];
    float Mn = fminf(fminf(red5[0][3],red5[1][3]), fminf(red5[2][3],red5[3][3]));
    float Mx = fmaxf(fmaxf(red5[0][4],red5[1][4]), fmaxf(red5[2][4],red5[3][4]));
    atomicAdd(&S[0], S0); atomicAdd(&S[1], S1); atomicAdd(&S[2], S2);
    atomicMin((u32*)S + 3, fkey(Mn));
    atomicMax((u32*)S + 4, fkey(Mx));
  }
}

// ---------- K2: fused prep + message-pass + cell + readout ----------
// k_prep absorbed: each block stages t-params, lane 0 runs the t-regulator MLP
// from the global e-stats in S (identical in every block), then 64 threads
// build the normalized sparse adjacency in LDS. ~600 extra VALU ops/block,
// hidden by cross-block overlap; saves one kernel launch + k_prep dispatch.
// NO min-waves launch bound (r3 (256,5) and r4 (256,4) both spilled:
// 377MB / 213MB scratch). Natural allocation (r2: VGPR 108) is clean.
__global__ __launch_bounds__(256) void k_cell(const u16* __restrict__ E,
    const u16* __restrict__ WsB, const u16* __restrict__ WfB,
    const float* __restrict__ adjw,
    const float* __restrict__ lng, const float* __restrict__ lnb,
    const float* __restrict__ Wread, const float* __restrict__ bread,
    const float* __restrict__ S,
    const float* tW1, const float* tb1, const float* tg1, const float* tbb1,
    const float* tW2, const float* tb2, const float* tg2, const float* tbb2,
    const float* tW3, const float* tb3,
    const float* cW1, const float* cb1, const float* cg1, const float* cbb1,
    const float* cW2, const float* cb2, const float* cg2, const float* cbb2,
    const float* cW3, const float* cb3,
    float* __restrict__ out) {
  __shared__ __align__(16) u16 ebM[64][72];   // e -> m (overlay); cols 64..71 = per-row f32x4 scratch
  __shared__ __align__(16) u16 WsH[64][72];   // W_slow bf16 [j][d]
  __shared__ __align__(16) u16 WfH[64][72];
  __shared__ __align__(16) float adjcL[256];
  __shared__ __align__(16) float prm[308];    // c-params
  __shared__ __align__(16) float tprm[308];   // t-params
  __shared__ __align__(16) float lngL[64], lnbL[64];
  __shared__ float wavp[4][10];
  __shared__ float wncL, apS;

  const int t = threadIdx.x;
  const int wv = t >> 6, lane = t & 63;
  const int b = blockIdx.x;
  const u16* Eb = E + (size_t)b * 4096;

  // ---- P1: loads (16 u16 per thread per matrix, quarter-row chunks) ----
  {
    const int row = t >> 2, c16 = (t & 3) * 16;
    *(i32x4*)&ebM[row][c16]     = *(const i32x4*)(Eb  + row*64 + c16);
    *(i32x4*)&ebM[row][c16 + 8] = *(const i32x4*)(Eb  + row*64 + c16 + 8);
    *(i32x4*)&WsH[row][c16]     = *(const i32x4*)(WsB + row*64 + c16);
    *(i32x4*)&WsH[row][c16 + 8] = *(const i32x4*)(WsB + row*64 + c16 + 8);
    *(i32x4*)&WfH[row][c16]     = *(const i32x4*)(WfB + row*64 + c16);
    *(i32x4*)&WfH[row][c16 + 8] = *(const i32x4*)(WfB + row*64 + c16 + 8);
  }
  for (int i = t; i < 80;  i += 256) { prm[i] = cW1[i]; tprm[i] = tW1[i]; }
  if (t < 16) { prm[80+t]=cb1[t]; prm[96+t]=cg1[t]; prm[112+t]=cbb1[t];
                tprm[80+t]=tb1[t]; tprm[96+t]=tg1[t]; tprm[112+t]=tbb1[t]; }
  for (int i = t; i < 128; i += 256) { prm[128+i] = cW2[i]; tprm[128+i] = tW2[i]; }
  if (t < 8)  { prm[256+t]=cb2[t]; prm[264+t]=cg2[t]; prm[272+t]=cbb2[t];
                tprm[256+t]=tb2[t]; tprm[264+t]=tg2[t]; tprm[272+t]=tbb2[t]; }
  if (t < 24) { prm[280+t] = cW3[t]; tprm[280+t] = tW3[t]; }
  if (t < 3)  { prm[304+t] = cb3[t]; tprm[304+t] = tb3[t]; }
  if (t < 64) { lngL[t] = lng[t]; lnbL[t] = lnb[t]; }
  if (t == 0) wncL = S[7];
  __syncthreads();

  // ---- P0: t-regulator MLP (lane 0) from global e-stats -> ap ----
  if (t == 0) {
    const float n = 16777216.0f, n1 = 16777215.0f;
    float sum = S[0], sumsq = S[1], sumabs = S[2];
    float mean = sum / n;
    float var = (sumsq - sum*mean) / n1;             // ddof=1
    float mn = unkey(((const u32*)S)[3]);
    float mx = unkey(((const u32*)S)[4]);
    float sfv[5];
    sfv[0] = fabsf(var - 0.5f);
    sfv[1] = fabsf((mx - mn)/n1 - 1.0f);             // sort-free smoothness
    sfv[2] = sumabs / n;
    sfv[3] = S[5];                                    // wn_t
    sfv[4] = sqrtf(sumsq / n);
    MlpP p{tprm, tprm+80, tprm+96, tprm+112, tprm+128, tprm+256, tprm+264, tprm+272, tprm+280, tprm+304};
    float ctl[3];
    mlp_eval(p, sfv, ctl);
    apS = ctl[0];
  }
  __syncthreads();

  // ---- P0b: normalized sparse adjacency (64 threads, 4 neighbors each) ----
  if (t < 64) {
    const int gr = t >> 3, gc = t & 7;
    const float ap = apS;
    const int nb[4] = { gr>0 ? t-8 : -1, gr<7 ? t+8 : -1, gc>0 ? t-1 : -1, gc<7 ? t+1 : -1 };
    float w4[4]; float rs = 0.f;
    #pragma unroll
    for (int qq = 0; qq < 4; ++qq) {
      w4[qq] = (nb[qq] >= 0) ? sigm(adjw[t*64 + nb[qq]] * ap) : 0.0f;
      rs += w4[qq];
    }
    rs = fmaxf(rs, 1e-6f);
    #pragma unroll
    for (int qq = 0; qq < 4; ++qq) adjcL[t*4 + qq] = w4[qq] / rs;
  }
  __syncthreads();

  // ---- P2: message passing into registers; wave wv owns nodes wv*16..+15 ----
  float macc[16];
  {
    const int d = lane;
    #pragma unroll
    for (int i = 0; i < 16; ++i) {
      const int n = wv*16 + i;
      const int gr = n >> 3, gc = n & 7;
      const int nb0 = gr > 0 ? n - 8 : 0;
      const int nb1 = gr < 7 ? n + 8 : 0;
      const int nb2 = gc > 0 ? n - 1 : 0;
      const int nb3 = gc < 7 ? n + 1 : 0;
      macc[i] = adjcL[n*4+0]*bf2f(ebM[nb0][d]) + adjcL[n*4+1]*bf2f(ebM[nb1][d])
              + adjcL[n*4+2]*bf2f(ebM[nb2][d]) + adjcL[n*4+3]*bf2f(ebM[nb3][d]);
    }
  }
  __syncthreads();   // all e reads done
  #pragma unroll
  for (int i = 0; i < 16; ++i) ebM[wv*16 + i][lane] = f2bf(macc[i]);  // m overlays e
  __syncthreads();

  // ---- P3: MFMA hsT/hfT; frags feed stats ----
  const int rr = lane & 15, q = lane >> 4;
  const int n = wv*16 + rr;
  s8v bm0 = *(const s8v*)&ebM[n][q*8];
  s8v bm1 = *(const s8v*)&ebM[n][32 + q*8];
  f32x4 hs[4], hf[4];
  #pragma unroll
  for (int jt = 0; jt < 4; ++jt) {
    const u16* wsr = &WsH[jt*16 + rr][0];
    const u16* wfr = &WfH[jt*16 + rr][0];
    s8v aw0 = *(const s8v*)(wsr + q*8), aw1 = *(const s8v*)(wsr + 32 + q*8);
    s8v af0 = *(const s8v*)(wfr + q*8), af1 = *(const s8v*)(wfr + 32 + q*8);
    f32x4 z = {0.f, 0.f, 0.f, 0.f};
    hs[jt] = __builtin_amdgcn_mfma_f32_16x16x32_bf16(aw0, bm0, z, 0, 0, 0);
    hs[jt] = __builtin_amdgcn_mfma_f32_16x16x32_bf16(aw1, bm1, hs[jt], 0, 0, 0);
    hf[jt] = __builtin_amdgcn_mfma_f32_16x16x32_bf16(af0, bm0, z, 0, 0, 0);
    hf[jt] = __builtin_amdgcn_mfma_f32_16x16x32_bf16(af1, bm1, hf[jt], 0, 0, 0);
  }

  // ---- P4: per-node stats (reduce over q); q==0 lane stores into own row pad ----
  float s1 = 0.f, s2 = 0.f, mnv = 1e30f, mxv = -1e30f;
  #pragma unroll
  for (int j = 0; j < 8; ++j) {
    float v0 = bf2f((u16)bm0[j]), v1 = bf2f((u16)bm1[j]);
    s1 += v0 + v1;
    s2 = fmaf(v0, v0, s2); s2 = fmaf(v1, v1, s2);
    mnv = fminf(mnv, fminf(v0, v1));
    mxv = fmaxf(mxv, fmaxf(v0, v1));
  }
  float sa = 0.f, sq = 0.f;
  #pragma unroll
  for (int jt = 0; jt < 4; ++jt)
    #pragma unroll
    for (int r = 0; r < 4; ++r) { float v = hs[jt][r]; sa += fabsf(v); sq = fmaf(v, v, sq); }
  #pragma unroll
  for (int off = 16; off <= 32; off <<= 1) {
    s1 += __shfl_xor(s1, off); s2 += __shfl_xor(s2, off);
    sa += __shfl_xor(sa, off); sq += __shfl_xor(sq, off);
    mnv = fminf(mnv, __shfl_xor(mnv, off));
    mxv = fmaxf(mxv, __shfl_xor(mxv, off));
  }
  if (q == 0) {
    float var = (s2 - s1*s1*(1.f/64.f)) * (1.f/63.f);   // ddof=1
    f32x4 sv = { fabsf(var - 0.5f),
                 fabsf((mxv - mnv)*(1.f/63.f) - 1.f),
                 sa * (1.f/64.f),
                 sqrtf(sq * (1.f/64.f)) };
    *(f32x4*)&ebM[n][64] = sv;                          // own wave's row: race-free
  }
  __syncthreads();

  // ---- P4b: ONE wave computes all 64 node-MLPs (lane = node) ----
  if (t < 64) {
    f32x4 sv = *(const f32x4*)&ebM[t][64];
    float sfv[5] = { sv[0], sv[1], sv[2], wncL, sv[3] };
    MlpP p{prm, prm+80, prm+96, prm+112, prm+128, prm+256, prm+264, prm+272, prm+280, prm+304};
    float ctl[3];
    mlp_eval(p, sfv, ctl);
    float* pad = (float*)&ebM[t][64];
    pad[0] = 0.5f + 2.f*ctl[1];                         // beta
    pad[1] = ctl[2];                                    // gate
  }
  __syncthreads();

  // ---- P5: comb -> swish -> LN -> fused readout ----
  const float beta = ((const float*)&ebM[n][64])[0];
  const float gate = ((const float*)&ebM[n][64])[1];
  float acts[4][4];
  float a1 = 0.f, a2 = 0.f;
  #pragma unroll
  for (int jt = 0; jt < 4; ++jt)
    #pragma unroll
    for (int r = 0; r < 4; ++r) {
      float comb = fmaf(hf[jt][r], gate, hs[jt][r]);
      float sv = comb * sigm(beta * comb);
      acts[jt][r] = sv;
      a1 += sv; a2 = fmaf(sv, sv, a2);
    }
  a1 += __shfl_xor(a1, 16); a2 += __shfl_xor(a2, 16);
  a1 += __shfl_xor(a1, 32); a2 += __shfl_xor(a2, 32);
  float mu = a1 * (1.f/64.f);
  float vvv = a2 * (1.f/64.f) - mu*mu;                 // ddof=0
  float inv = 1.f / sqrtf(vvv + 1e-5f);
  float racc[10];
  #pragma unroll
  for (int c = 0; c < 10; ++c) racc[c] = 0.f;
  #pragma unroll
  for (int jt = 0; jt < 4; ++jt) {
    f32x4 gv = *(const f32x4*)&lngL[jt*16 + q*4];
    f32x4 bv = *(const f32x4*)&lnbL[jt*16 + q*4];
    float pr[4];
    #pragma unroll
    for (int r = 0; r < 4; ++r) pr[r] = (acts[jt][r] - mu)*inv*gv[r] + bv[r];
    const float* wrb = Wread + n*64 + jt*16 + q*4;
    #pragma unroll
    for (int c = 0; c < 10; ++c) {
      f32x4 w = *(const f32x4*)(wrb + c*4096);
      racc[c] += pr[0]*w[0] + pr[1]*w[1] + pr[2]*w[2] + pr[3]*w[3];
    }
  }
  #pragma unroll
  for (int c = 0; c < 10; ++c) {
    float v = racc[c];
    #pragma unroll
    for (int off = 1; off < 64; off <<= 1) v += __shfl_xor(v, off);
    if (lane == 0) wavp[wv][c] = v;
  }
  __syncthreads();
  if (t < 10) out[(size_t)b*10 + t] = bread[t] + wavp[0][t] + wavp[1][t] + wavp[2][t] + wavp[3][t];
}

// ---------- launcher ----------
extern "C" void kernel_launch(void* const* d_in, const int* in_sizes, int n_in,
                              void* d_out, int out_size, void* d_ws, size_t ws_size,
                              hipStream_t stream) {
  (void)in_sizes; (void)n_in; (void)out_size; (void)ws_size;
  const float* x       = (const float*)d_in[0];
  const float* W_embed = (const float*)d_in[1];
  const float* b_embed = (const float*)d_in[2];
  const float* adjw    = (const float*)d_in[3];
  const float* Wslow   = (const float*)d_in[4];
  const float* Wfast   = (const float*)d_in[5];
  const float* lng     = (const float*)d_in[6];
  const float* lnb     = (const float*)d_in[7];
  const float* Wread   = (const float*)d_in[8];
  const float* bread   = (const float*)d_in[9];
  float* out = (float*)d_out;

  char* ws = (char*)d_ws;
  u16*   Ebf  = (u16*)ws;                              // 33554432 B
  u16*   Xbf  = (u16*)(ws + 33554432);                 // 2097152 B
  u16*   Wbf  = (u16*)(ws + 35651584);                 // 2097152 B
  float* S    = (float*)(ws + 37748736);               // stats
  u16*   WsBf = (u16*)(ws + 37752832);                 // 8192 B
  u16*   WfBf = (u16*)(ws + 37761024);                 // 8192 B

  hipLaunchKernelGGL(k_pre, dim3(2049), dim3(256), 0, stream,
                     x, W_embed, Wslow, Wfast, adjw, Xbf, Wbf, WsBf, WfBf, S);
  hipLaunchKernelGGL(k_gemm, dim3(1024), dim3(256), 0, stream, Xbf, Wbf, b_embed, Ebf, S);
  hipLaunchKernelGGL(k_cell, dim3(4096), dim3(256), 0, stream, Ebf, WsBf, WfBf, adjw,
                     lng, lnb, Wread, bread, S,
                     (const float*)d_in[10], (const float*)d_in[11], (const float*)d_in[12], (const float*)d_in[13],
                     (const float*)d_in[14], (const float*)d_in[15], (const float*)d_in[16], (const float*)d_in[17],
                     (const float*)d_in[18], (const float*)d_in[19],
                     (const float*)d_in[20], (const float*)d_in[21], (const float*)d_in[22], (const float*)d_in[23],
                     (const float*)d_in[24], (const float*)d_in[25], (const float*)d_in[26], (const float*)d_in[27],
                     (const float*)d_in[28], (const float*)d_in[29], out);
}

// Round 8
// 332.826 us; speedup vs baseline: 1.5345x; 1.0499x over previous
//
#include <hip/hip_runtime.h>

typedef unsigned short u16;
typedef unsigned int   u32;
typedef float f32x4 __attribute__((ext_vector_type(4)));
typedef int   i32x4 __attribute__((ext_vector_type(4)));
typedef int   i32x2 __attribute__((ext_vector_type(2)));
typedef short s8v   __attribute__((ext_vector_type(8)));

// ---------- helpers ----------
__device__ inline u16 f2bf(float f) {
  u32 u = __float_as_uint(f);
  return (u16)((u + 0x7FFFu + ((u >> 16) & 1u)) >> 16);
}
__device__ inline float bf2f(u16 h) { return __uint_as_float(((u32)h) << 16); }

__device__ inline u32 fkey(float f) {
  u32 u = __float_as_uint(f);
  return (u & 0x80000000u) ? ~u : (u | 0x80000000u);
}
__device__ inline float unkey(u32 k) {
  u32 u = (k & 0x80000000u) ? (k & 0x7FFFFFFFu) : ~k;
  return __uint_as_float(u);
}
__device__ inline float fast_tanh(float x) {
  float cx = fminf(fmaxf(x, -15.f), 15.f);
  float e = __expf(2.f * cx);
  return __fdividef(e - 1.f, e + 1.f);
}
__device__ inline float sigm(float x) { return __fdividef(1.f, 1.f + __expf(-x)); }

__device__ inline void gload_lds16(const u16* g, u16* l) {
  __builtin_amdgcn_global_load_lds((const __attribute__((address_space(1))) u32*)g,
                                   (__attribute__((address_space(3))) u32*)l, 16, 0, 0);
}

struct MlpP { const float *W1,*b1,*g1,*bb1,*W2,*b2,*g2,*bb2,*W3,*b3; };

// 5 -> 16(LN,tanh) -> 8(LN,tanh) -> 3(sigmoid)
__device__ inline void mlp_eval(const MlpP& p, const float* s, float* ctl) {
  float h1[16];
  float mu = 0.f;
  #pragma unroll
  for (int i = 0; i < 16; ++i) {
    float v = p.b1[i];
    #pragma unroll
    for (int k = 0; k < 5; ++k) v = fmaf(p.W1[i*5+k], s[k], v);
    h1[i] = v; mu += v;
  }
  mu *= (1.0f/16.0f);
  float vv = 0.f;
  #pragma unroll
  for (int i = 0; i < 16; ++i) { float d = h1[i]-mu; vv += d*d; }
  vv *= (1.0f/16.0f);
  float inv = 1.0f/sqrtf(vv + 1e-5f);
  #pragma unroll
  for (int i = 0; i < 16; ++i) h1[i] = fast_tanh((h1[i]-mu)*inv*p.g1[i] + p.bb1[i]);
  float h2[8];
  mu = 0.f;
  #pragma unroll
  for (int o = 0; o < 8; ++o) {
    float v = p.b2[o];
    #pragma unroll
    for (int i = 0; i < 16; ++i) v = fmaf(p.W2[o*16+i], h1[i], v);
    h2[o] = v; mu += v;
  }
  mu *= 0.125f;
  vv = 0.f;
  #pragma unroll
  for (int o = 0; o < 8; ++o) { float d = h2[o]-mu; vv += d*d; }
  vv *= 0.125f;
  inv = 1.0f/sqrtf(vv + 1e-5f);
  #pragma unroll
  for (int o = 0; o < 8; ++o) h2[o] = fast_tanh((h2[o]-mu)*inv*p.g2[o] + p.bb2[o]);
  #pragma unroll
  for (int c = 0; c < 3; ++c) {
    float v = p.b3[c];
    #pragma unroll
    for (int o = 0; o < 8; ++o) v = fmaf(p.W3[c*8+o], h2[o], v);
    ctl[c] = sigm(v);
  }
}

// ---------- K0: merged pre-kernel: cast X/W_embed/Ws/Wf, norms, init S ----------
__global__ __launch_bounds__(256) void k_pre(const float* __restrict__ x,
                                             const float* __restrict__ We,
                                             const float* __restrict__ Ws,
                                             const float* __restrict__ Wf,
                                             const float* __restrict__ adjw,
                                             u16* __restrict__ Xb, u16* __restrict__ Wb,
                                             u16* __restrict__ WsB, u16* __restrict__ WfB,
                                             float* __restrict__ S) {
  const int bi = blockIdx.x, t = threadIdx.x;
  if (bi < 2048) {
    const float* src = (bi < 1024) ? x : We;
    u16* dst = (bi < 1024) ? Xb : Wb;
    int i = ((bi & 1023) * 256 + t) * 4;
    f32x4 v = *(const f32x4*)(src + i);
    u16 o[4] = { f2bf(v[0]), f2bf(v[1]), f2bf(v[2]), f2bf(v[3]) };
    *(u32*)(dst + i)     = ((u32)o[1] << 16) | o[0];
    *(u32*)(dst + i + 2) = ((u32)o[3] << 16) | o[2];
  } else {
    // cast W_slow / W_fast (4096 elems each): 16 elems per thread
    #pragma unroll
    for (int m = 0; m < 2; ++m) {
      const float* src = m ? Wf : Ws;
      u16* dst = m ? WfB : WsB;
      int base = t * 16;
      u16 o[16];
      #pragma unroll
      for (int r = 0; r < 4; ++r) {
        f32x4 v = *(const f32x4*)(src + base + r*4);
        o[r*4+0]=f2bf(v[0]); o[r*4+1]=f2bf(v[1]); o[r*4+2]=f2bf(v[2]); o[r*4+3]=f2bf(v[3]);
      }
      #pragma unroll
      for (int r = 0; r < 8; ++r)
        *(u32*)(dst + base + r*2) = ((u32)o[r*2+1] << 16) | o[r*2];
    }
    // Frobenius norms of adj_weights (wn_t) and W_slow (wn_c)
    __shared__ float red2[2][256];
    float a = 0.f, w = 0.f;
    for (int i = t; i < 4096; i += 256) {
      float v = adjw[i]; a = fmaf(v, v, a);
      float u = Ws[i];   w = fmaf(u, u, w);
    }
    red2[0][t] = a; red2[1][t] = w;
    __syncthreads();
    for (int sred = 128; sred > 0; sred >>= 1) {
      if (t < sred) { red2[0][t] += red2[0][t+sred]; red2[1][t] += red2[1][t+sred]; }
      __syncthreads();
    }
    if (t == 0) { S[5] = sqrtf(red2[0][0]); S[7] = sqrtf(red2[1][0]); }
    if (t < 3) S[t] = 0.f;
    if (t == 3) ((u32*)S)[3] = 0xFFFFFFFFu;  // min key
    if (t == 4) ((u32*)S)[4] = 0u;           // max key
  }
}

// ---------- K1: e = x @ W_embed.T + b_embed, fused global stats ----------
// r2-proven structure: 128x128 tile, BK=64, single-buffer 32KB LDS,
// global_load_lds w=16, bijective XCD swizzle (1024%8==0). Unchanged from r7.
__global__ __launch_bounds__(256) void k_gemm(const u16* __restrict__ Xb,
                                              const u16* __restrict__ Wb,
                                              const float* __restrict__ bias,
                                              u16* __restrict__ E,
                                              float* __restrict__ S) {
  __shared__ __align__(16) u16 As[128*64];
  __shared__ __align__(16) u16 Bs[128*64];
  const int t = threadIdx.x;
  const int wv = t >> 6, lane = t & 63;
  const int wr = wv >> 1, wc = wv & 1;
  const int bid = blockIdx.x;
  const int sw = (bid & 7) * 128 + (bid >> 3);     // bijective: 1024 % 8 == 0
  const int i0 = (sw >> 5) * 128, j0 = (sw & 31) * 128;
  const int rr = lane & 15, q = lane >> 4;
  const int lrow = lane >> 3, lcol = (lane & 7) * 8;
  f32x4 acc[4][4] = {};
  for (int k0 = 0; k0 < 256; k0 += 64) {
    #pragma unroll
    for (int r = 0; r < 4; ++r) {
      const int row = (r*4 + wv)*8 + lrow;
      gload_lds16(Xb + (size_t)(i0 + row)*256 + k0 + lcol, &As[(r*4 + wv)*512]);
      gload_lds16(Wb + (size_t)(j0 + row)*256 + k0 + lcol, &Bs[(r*4 + wv)*512]);
    }
    __syncthreads();
    #pragma unroll
    for (int ks = 0; ks < 2; ++ks) {
      s8v a[4], b[4];
      #pragma unroll
      for (int m = 0; m < 4; ++m) a[m] = *(const s8v*)&As[(wr*64 + m*16 + rr)*64 + ks*32 + q*8];
      #pragma unroll
      for (int n = 0; n < 4; ++n) b[n] = *(const s8v*)&Bs[(wc*64 + n*16 + rr)*64 + ks*32 + q*8];
      #pragma unroll
      for (int m = 0; m < 4; ++m)
        #pragma unroll
        for (int n = 0; n < 4; ++n)
          acc[m][n] = __builtin_amdgcn_mfma_f32_16x16x32_bf16(a[m], b[n], acc[m][n], 0, 0, 0);
    }
    __syncthreads();
  }
  float s = 0.f, ss = 0.f, sa = 0.f, mnv = 1e30f, mxv = -1e30f;
  #pragma unroll
  for (int n = 0; n < 4; ++n) {
    const int col = j0 + wc*64 + n*16 + rr;
    const float bv = bias[col];
    #pragma unroll
    for (int m = 0; m < 4; ++m) {
      const int rowb = i0 + wr*64 + m*16 + q*4;
      #pragma unroll
      for (int r = 0; r < 4; ++r) {
        float v = acc[m][n][r] + bv;
        E[(size_t)(rowb + r)*4096 + col] = f2bf(v);
        s += v; ss = fmaf(v, v, ss); sa += fabsf(v);
        mnv = fminf(mnv, v); mxv = fmaxf(mxv, v);
      }
    }
  }
  #pragma unroll
  for (int off = 32; off; off >>= 1) {
    s += __shfl_xor(s, off); ss += __shfl_xor(ss, off); sa += __shfl_xor(sa, off);
    mnv = fminf(mnv, __shfl_xor(mnv, off));
    mxv = fmaxf(mxv, __shfl_xor(mxv, off));
  }
  __shared__ float red5[4][5];
  if (lane == 0) { red5[wv][0]=s; red5[wv][1]=ss; red5[wv][2]=sa; red5[wv][3]=mnv; red5[wv][4]=mxv; }
  __syncthreads();
  if (t == 0) {
    float S0 = red5[0][0]+red5[1][0]+red5[2][0]+red5[3][0];
    float S1 = red5[0][1]+red5[1][1]+red5[2][1]+red5[3][1];
    float S2 = red5[0][2]+red5[1][2]+red5[2][2]+red5[3][2];
    float Mn = fminf(fminf(red5[0][3],red5[1][3]), fminf(red5[2][3],red5[3][3]));
    float Mx = fmaxf(fmaxf(red5[0][4],red5[1][4]), fmaxf(red5[2][4],red5[3][4]));
    atomicAdd(&S[0], S0); atomicAdd(&S[1], S1); atomicAdd(&S[2], S2);
    atomicMin((u32*)S + 3, fkey(Mn));
    atomicMax((u32*)S + 4, fkey(Mx));
  }
}

// ---------- K2: lean prep (1 block, 64 threads): t-MLP -> ap -> adjacency ----------
// Restored as a separate tiny kernel: r7 proved absorbing it into k_cell put a
// ~600-op serial MLP + 2 barriers on every block's critical path (+24 us).
__global__ __launch_bounds__(64) void k_prep(const float* __restrict__ adjw,
    const float* tW1, const float* tb1, const float* tg1, const float* tbb1,
    const float* tW2, const float* tb2, const float* tg2, const float* tbb2,
    const float* tW3, const float* tb3,
    float* __restrict__ S) {
  __shared__ float apS;
  const int t = threadIdx.x;
  if (t == 0) {
    const float n = 16777216.0f, n1 = 16777215.0f;
    float sum = S[0], sumsq = S[1], sumabs = S[2];
    float mean = sum / n;
    float var = (sumsq - sum*mean) / n1;             // ddof=1
    float mn = unkey(((const u32*)S)[3]);
    float mx = unkey(((const u32*)S)[4]);
    float sfv[5];
    sfv[0] = fabsf(var - 0.5f);
    sfv[1] = fabsf((mx - mn)/n1 - 1.0f);             // sort-free smoothness
    sfv[2] = sumabs / n;
    sfv[3] = S[5];                                    // wn_t (from k_pre)
    sfv[4] = sqrtf(sumsq / n);
    MlpP p{tW1,tb1,tg1,tbb1,tW2,tb2,tg2,tbb2,tW3,tb3};
    float ctl[3];
    mlp_eval(p, sfv, ctl);
    apS = ctl[0];
  }
  __syncthreads();
  {
    const int gr = t >> 3, gc = t & 7;
    const float ap = apS;
    const int nb[4] = { gr>0 ? t-8 : -1, gr<7 ? t+8 : -1, gc>0 ? t-1 : -1, gc<7 ? t+1 : -1 };
    float w4[4]; float rs = 0.f;
    #pragma unroll
    for (int qq = 0; qq < 4; ++qq) {
      w4[qq] = (nb[qq] >= 0) ? sigm(adjw[t*64 + nb[qq]] * ap) : 0.0f;
      rs += w4[qq];
    }
    rs = fmaxf(rs, 1e-6f);
    #pragma unroll
    for (int qq = 0; qq < 4; ++qq) S[8 + t*4 + qq] = w4[qq] / rs;
  }
}

// ---------- K3: fused message-pass + cell + readout, v6 ----------
// r2-proven structure: stats live in registers after the q-reduce shuffles, so
// ALL 256 lanes compute the c-MLP redundantly (4 lanes/node) with NO extra
// barriers and NO LDS round-trip (r7's one-wave MLP + absorbed prep cost
// +24 us of critical-path latency at 21% occupancy). Pre-cast bf16 weights.
// NO min-waves launch bound (r3 (256,5) / r4 (256,4) both spilled: 377/213 MB).
__global__ __launch_bounds__(256) void k_cell(const u16* __restrict__ E,
    const u16* __restrict__ WsB, const u16* __restrict__ WfB,
    const float* __restrict__ lng, const float* __restrict__ lnb,
    const float* __restrict__ Wread, const float* __restrict__ bread,
    const float* __restrict__ S,
    const float* cW1, const float* cb1, const float* cg1, const float* cbb1,
    const float* cW2, const float* cb2, const float* cg2, const float* cbb2,
    const float* cW3, const float* cb3,
    float* __restrict__ out) {
  __shared__ __align__(16) u16 ebM[64][72];   // e -> m (overlay after P2)
  __shared__ __align__(16) u16 WsH[64][72];   // W_slow bf16 [j][d]
  __shared__ __align__(16) u16 WfH[64][72];
  __shared__ __align__(16) float adjcL[256];
  __shared__ __align__(16) float prm[308];    // c-params
  __shared__ __align__(16) float lngL[64], lnbL[64];
  __shared__ float wavp[4][10];
  __shared__ float wncL;

  const int t = threadIdx.x;
  const int wv = t >> 6, lane = t & 63;
  const int b = blockIdx.x;
  const u16* Eb = E + (size_t)b * 4096;

  // ---- P1: loads (16 u16 per thread per matrix, quarter-row chunks) ----
  {
    const int row = t >> 2, c16 = (t & 3) * 16;
    *(i32x4*)&ebM[row][c16]     = *(const i32x4*)(Eb  + row*64 + c16);
    *(i32x4*)&ebM[row][c16 + 8] = *(const i32x4*)(Eb  + row*64 + c16 + 8);
    *(i32x4*)&WsH[row][c16]     = *(const i32x4*)(WsB + row*64 + c16);
    *(i32x4*)&WsH[row][c16 + 8] = *(const i32x4*)(WsB + row*64 + c16 + 8);
    *(i32x4*)&WfH[row][c16]     = *(const i32x4*)(WfB + row*64 + c16);
    *(i32x4*)&WfH[row][c16 + 8] = *(const i32x4*)(WfB + row*64 + c16 + 8);
  }
  adjcL[t] = S[8 + t];
  for (int i = t; i < 80;  i += 256) prm[i] = cW1[i];
  if (t < 16) { prm[80+t]=cb1[t]; prm[96+t]=cg1[t]; prm[112+t]=cbb1[t]; }
  for (int i = t; i < 128; i += 256) prm[128+i] = cW2[i];
  if (t < 8)  { prm[256+t]=cb2[t]; prm[264+t]=cg2[t]; prm[272+t]=cbb2[t]; }
  if (t < 24) prm[280+t] = cW3[t];
  if (t < 3)  prm[304+t] = cb3[t];
  if (t < 64) { lngL[t] = lng[t]; lnbL[t] = lnb[t]; }
  if (t == 0) wncL = S[7];
  __syncthreads();

  // ---- P2: message passing into registers; wave wv owns nodes wv*16..+15 ----
  float macc[16];
  {
    const int d = lane;
    #pragma unroll
    for (int i = 0; i < 16; ++i) {
      const int n = wv*16 + i;
      const int gr = n >> 3, gc = n & 7;
      const int nb0 = gr > 0 ? n - 8 : 0;
      const int nb1 = gr < 7 ? n + 8 : 0;
      const int nb2 = gc > 0 ? n - 1 : 0;
      const int nb3 = gc < 7 ? n + 1 : 0;
      macc[i] = adjcL[n*4+0]*bf2f(ebM[nb0][d]) + adjcL[n*4+1]*bf2f(ebM[nb1][d])
              + adjcL[n*4+2]*bf2f(ebM[nb2][d]) + adjcL[n*4+3]*bf2f(ebM[nb3][d]);
    }
  }
  __syncthreads();   // all e reads done
  #pragma unroll
  for (int i = 0; i < 16; ++i) ebM[wv*16 + i][lane] = f2bf(macc[i]);  // m overlays e
  __syncthreads();

  // ---- P3: MFMA hsT/hfT; frags feed stats ----
  const int rr = lane & 15, q = lane >> 4;
  const int n = wv*16 + rr;
  s8v bm0 = *(const s8v*)&ebM[n][q*8];
  s8v bm1 = *(const s8v*)&ebM[n][32 + q*8];
  f32x4 hs[4], hf[4];
  #pragma unroll
  for (int jt = 0; jt < 4; ++jt) {
    const u16* wsr = &WsH[jt*16 + rr][0];
    const u16* wfr = &WfH[jt*16 + rr][0];
    s8v aw0 = *(const s8v*)(wsr + q*8), aw1 = *(const s8v*)(wsr + 32 + q*8);
    s8v af0 = *(const s8v*)(wfr + q*8), af1 = *(const s8v*)(wfr + 32 + q*8);
    f32x4 z = {0.f, 0.f, 0.f, 0.f};
    hs[jt] = __builtin_amdgcn_mfma_f32_16x16x32_bf16(aw0, bm0, z, 0, 0, 0);
    hs[jt] = __builtin_amdgcn_mfma_f32_16x16x32_bf16(aw1, bm1, hs[jt], 0, 0, 0);
    hf[jt] = __builtin_amdgcn_mfma_f32_16x16x32_bf16(af0, bm0, z, 0, 0, 0);
    hf[jt] = __builtin_amdgcn_mfma_f32_16x16x32_bf16(af1, bm1, hf[jt], 0, 0, 0);
  }

  // ---- P4: per-node stats (reduce over q); ALL lanes run the MLP in regs ----
  float s1 = 0.f, s2 = 0.f, mnv = 1e30f, mxv = -1e30f;
  #pragma unroll
  for (int j = 0; j < 8; ++j) {
    float v0 = bf2f((u16)bm0[j]), v1 = bf2f((u16)bm1[j]);
    s1 += v0 + v1;
    s2 = fmaf(v0, v0, s2); s2 = fmaf(v1, v1, s2);
    mnv = fminf(mnv, fminf(v0, v1));
    mxv = fmaxf(mxv, fmaxf(v0, v1));
  }
  float sa = 0.f, sq = 0.f;
  #pragma unroll
  for (int jt = 0; jt < 4; ++jt)
    #pragma unroll
    for (int r = 0; r < 4; ++r) { float v = hs[jt][r]; sa += fabsf(v); sq = fmaf(v, v, sq); }
  #pragma unroll
  for (int off = 16; off <= 32; off <<= 1) {
    s1 += __shfl_xor(s1, off); s2 += __shfl_xor(s2, off);
    sa += __shfl_xor(sa, off); sq += __shfl_xor(sq, off);
    mnv = fminf(mnv, __shfl_xor(mnv, off));
    mxv = fmaxf(mxv, __shfl_xor(mxv, off));
  }
  float var = (s2 - s1*s1*(1.f/64.f)) * (1.f/63.f);   // ddof=1
  float sfv[5];
  sfv[0] = fabsf(var - 0.5f);
  sfv[1] = fabsf((mxv - mnv)*(1.f/63.f) - 1.f);
  sfv[2] = sa * (1.f/64.f);
  sfv[3] = wncL;
  sfv[4] = sqrtf(sq * (1.f/64.f));
  MlpP p{prm, prm+80, prm+96, prm+112, prm+128, prm+256, prm+264, prm+272, prm+280, prm+304};
  float ctl[3];
  mlp_eval(p, sfv, ctl);
  const float beta = 0.5f + 2.f*ctl[1], gate = ctl[2];

  // ---- P5: comb -> swish -> LN -> fused readout, all from registers ----
  float acts[4][4];
  float a1 = 0.f, a2 = 0.f;
  #pragma unroll
  for (int jt = 0; jt < 4; ++jt)
    #pragma unroll
    for (int r = 0; r < 4; ++r) {
      float comb = fmaf(hf[jt][r], gate, hs[jt][r]);
      float sv = comb * sigm(beta * comb);
      acts[jt][r] = sv;
      a1 += sv; a2 = fmaf(sv, sv, a2);
    }
  a1 += __shfl_xor(a1, 16); a2 += __shfl_xor(a2, 16);
  a1 += __shfl_xor(a1, 32); a2 += __shfl_xor(a2, 32);
  float mu = a1 * (1.f/64.f);
  float vvv = a2 * (1.f/64.f) - mu*mu;                 // ddof=0
  float inv = 1.f / sqrtf(vvv + 1e-5f);
  float racc[10];
  #pragma unroll
  for (int c = 0; c < 10; ++c) racc[c] = 0.f;
  #pragma unroll
  for (int jt = 0; jt < 4; ++jt) {
    f32x4 gv = *(const f32x4*)&lngL[jt*16 + q*4];
    f32x4 bv = *(const f32x4*)&lnbL[jt*16 + q*4];
    float pr[4];
    #pragma unroll
    for (int r = 0; r < 4; ++r) pr[r] = (acts[jt][r] - mu)*inv*gv[r] + bv[r];
    const float* wrb = Wread + n*64 + jt*16 + q*4;
    #pragma unroll
    for (int c = 0; c < 10; ++c) {
      f32x4 w = *(const f32x4*)(wrb + c*4096);
      racc[c] += pr[0]*w[0] + pr[1]*w[1] + pr[2]*w[2] + pr[3]*w[3];
    }
  }
  #pragma unroll
  for (int c = 0; c < 10; ++c) {
    float v = racc[c];
    #pragma unroll
    for (int off = 1; off < 64; off <<= 1) v += __shfl_xor(v, off);
    if (lane == 0) wavp[wv][c] = v;
  }
  __syncthreads();
  if (t < 10) out[(size_t)b*10 + t] = bread[t] + wavp[0][t] + wavp[1][t] + wavp[2][t] + wavp[3][t];
}

// ---------- launcher ----------
extern "C" void kernel_launch(void* const* d_in, const int* in_sizes, int n_in,
                              void* d_out, int out_size, void* d_ws, size_t ws_size,
                              hipStream_t stream) {
  (void)in_sizes; (void)n_in; (void)out_size; (void)ws_size;
  const float* x       = (const float*)d_in[0];
  const float* W_embed = (const float*)d_in[1];
  const float* b_embed = (const float*)d_in[2];
  const float* adjw    = (const float*)d_in[3];
  const float* Wslow   = (const float*)d_in[4];
  const float* Wfast   = (const float*)d_in[5];
  const float* lng     = (const float*)d_in[6];
  const float* lnb     = (const float*)d_in[7];
  const float* Wread   = (const float*)d_in[8];
  const float* bread   = (const float*)d_in[9];
  float* out = (float*)d_out;

  char* ws = (char*)d_ws;
  u16*   Ebf  = (u16*)ws;                              // 33554432 B
  u16*   Xbf  = (u16*)(ws + 33554432);                 // 2097152 B
  u16*   Wbf  = (u16*)(ws + 35651584);                 // 2097152 B
  float* S    = (float*)(ws + 37748736);               // stats + adjc
  u16*   WsBf = (u16*)(ws + 37752832);                 // 8192 B
  u16*   WfBf = (u16*)(ws + 37761024);                 // 8192 B

  hipLaunchKernelGGL(k_pre, dim3(2049), dim3(256), 0, stream,
                     x, W_embed, Wslow, Wfast, adjw, Xbf, Wbf, WsBf, WfBf, S);
  hipLaunchKernelGGL(k_gemm, dim3(1024), dim3(256), 0, stream, Xbf, Wbf, b_embed, Ebf, S);
  hipLaunchKernelGGL(k_prep, dim3(1), dim3(64), 0, stream, adjw,
                     (const float*)d_in[10], (const float*)d_in[11], (const float*)d_in[12], (const float*)d_in[13],
                     (const float*)d_in[14], (const float*)d_in[15], (const float*)d_in[16], (const float*)d_in[17],
                     (const float*)d_in[18], (const float*)d_in[19], S);
  hipLaunchKernelGGL(k_cell, dim3(4096), dim3(256), 0, stream, Ebf, WsBf, WfBf,
                     lng, lnb, Wread, bread, S,
                     (const float*)d_in[20], (const float*)d_in[21], (const float*)d_in[22], (const float*)d_in[23],
                     (const float*)d_in[24], (const float*)d_in[25], (const float*)d_in[26], (const float*)d_in[27],
                     (const float*)d_in[28], (const float*)d_in[29], out);
}